// Round 1
// baseline (491.605 us; speedup 1.0000x reference)
//
#include <hip/hip_runtime.h>
#include <stdint.h>

#define LOG2E 1.44269504088896340f

typedef __attribute__((ext_vector_type(4))) float f32x4;
typedef __attribute__((ext_vector_type(8))) short bf16x8;

__device__ __forceinline__ unsigned int f2bf1(float f) {
  unsigned int u = __builtin_bit_cast(unsigned int, f);
  u += 0x7fffu + ((u >> 16) & 1u);   // RNE to bf16
  return u >> 16;
}
__device__ __forceinline__ unsigned int f2bf_pk(float lo, float hi) {
  return f2bf1(lo) | (f2bf1(hi) << 16);
}

// ---------------- prep kernels (run every call; deterministic) ----------------

// convert qkv_w / proj_w to bf16; fold q-scale (hd^-0.5) into q rows
__global__ void prep_wts(const float* __restrict__ qkv_w, const float* __restrict__ proj_w,
                         unsigned short* __restrict__ qkv_wb, unsigned short* __restrict__ proj_wb) {
  int i = blockIdx.x * blockDim.x + threadIdx.x;
  int stride = gridDim.x * blockDim.x;
  for (int idx = i; idx < 768 * 256; idx += stride) {
    float v = qkv_w[idx];
    if (idx < 256 * 256) v *= 0.17677669529663687f;  // 1/sqrt(32)
    qkv_wb[idx] = (unsigned short)f2bf1(v);
  }
  for (int idx = i; idx < 256 * 256; idx += stride)
    proj_wb[idx] = (unsigned short)f2bf1(proj_w[idx]);
}

// SwinV2 CPB MLP: t[225][8]  (one block per table row, 64 lanes split 512 hiddens)
__global__ void prep_cpb(const float* __restrict__ w1, const float* __restrict__ b1,
                         const float* __restrict__ w2, float* __restrict__ t_buf) {
  int row = blockIdx.x;        // 0..224
  int l = threadIdx.x;         // 0..63
  int a = row / 15, bb = row % 15;
  float va = (a - 7) * (8.0f / 7.0f);
  float vb = (bb - 7) * (8.0f / 7.0f);
  float x0 = (va > 0.f ? 1.f : (va < 0.f ? -1.f : 0.f)) * log2f(fabsf(va) + 1.0f) * (1.0f / 3.0f);
  float x1 = (vb > 0.f ? 1.f : (vb < 0.f ? -1.f : 0.f)) * log2f(fabsf(vb) + 1.0f) * (1.0f / 3.0f);
  float acc[8];
  #pragma unroll
  for (int o = 0; o < 8; o++) acc[o] = 0.f;
  for (int jj = 0; jj < 8; jj++) {
    int j = jj * 64 + l;
    float h = fmaf(x0, w1[2 * j], fmaf(x1, w1[2 * j + 1], b1[j]));
    h = fmaxf(h, 0.f);
    #pragma unroll
    for (int o = 0; o < 8; o++) acc[o] = fmaf(h, w2[o * 512 + j], acc[o]);
  }
  #pragma unroll
  for (int m = 1; m < 64; m <<= 1) {
    #pragma unroll
    for (int o = 0; o < 8; o++) acc[o] += __shfl_xor(acc[o], m, 64);
  }
  if (l < 8) t_buf[row * 8 + l] = acc[l];
}

// bias_sw[h][ti][tj][lane][jj] = 16*sigmoid(t[rel_idx[q][kv]][h]) in the exact
// register layout the S^T tiles use: q = tj*16+(lane&15), kv = ti*16+(lane>>4)*4+jj
__global__ void prep_bias(const float* __restrict__ t_buf, float* __restrict__ bias_sw) {
  int blk = blockIdx.x;   // h*16 + ti*4 + tj   (128 blocks)
  int l = threadIdx.x;    // 64
  int h = blk >> 4, ti = (blk >> 2) & 3, tj = blk & 3;
  int q = tj * 16 + (l & 15);
  int kvb = ti * 16 + (l >> 4) * 4;
  int qi = q >> 3, qj = q & 7;
  #pragma unroll
  for (int jj = 0; jj < 4; jj++) {
    int kv = kvb + jj, ki = kv >> 3, kj = kv & 7;
    int idx = (qi - ki + 7) * 15 + (qj - kj + 7);
    float tv = t_buf[idx * 8 + h];
    float s = 16.0f / (1.0f + exp2f(-tv * LOG2E));
    bias_sw[(blk * 64 + l) * 4 + jj] = s;
  }
}

// ---------------- fused main kernel ----------------
// grid 4096 (one window per block), 512 threads = 8 waves, wave w owns head w.
// LDS: per-wave {q[64][40], k[64][40], vT[32][72]} bf16 (P[64][72] overlays q+k)
//      + shared x/o buffer [64][264] bf16.  Total 152576 B -> 1 block/CU.
__global__ __launch_bounds__(512, 2)
void win_attn(const float* __restrict__ x, const unsigned short* __restrict__ qkv_wb,
              const unsigned short* __restrict__ proj_wb, const float* __restrict__ proj_b,
              const float* __restrict__ bias_sw, float* __restrict__ out) {
  extern __shared__ char smem[];
  const int b = blockIdx.x;
  const int tid = threadIdx.x;
  const int wid = tid >> 6;        // head
  const int lane = tid & 63;
  const int c = lane & 15, g = lane >> 4;
  const f32x4 fzero = {0.f, 0.f, 0.f, 0.f};

  unsigned short* qs  = (unsigned short*)(smem + wid * 14848);
  unsigned short* ks  = qs + 64 * 40;
  unsigned short* vTs = qs + 2 * 64 * 40;
  unsigned short* Ps  = qs;                                // overlays q+k after S
  unsigned short* xs  = (unsigned short*)(smem + 8 * 14848); // [64][264]; later O

  // ---- stage x -> LDS bf16 ----
  {
    const float* xb = x + (size_t)b * 16384;
    int row = tid >> 3, cb = (tid & 7) * 32;
    const float4* src = (const float4*)(xb + row * 256 + cb);
    #pragma unroll
    for (int qq = 0; qq < 4; qq++) {
      float4 f0 = src[2 * qq], f1 = src[2 * qq + 1];
      uint4 pk;
      pk.x = f2bf_pk(f0.x, f0.y);
      pk.y = f2bf_pk(f0.z, f0.w);
      pk.z = f2bf_pk(f1.x, f1.y);
      pk.w = f2bf_pk(f1.z, f1.w);
      *(uint4*)(xs + row * 264 + cb + qq * 8) = pk;
    }
  }
  __syncthreads();

  // ---- qkv GEMM: wave computes q,k,v (head wid), 6 col-tiles of 16 ----
  f32x4 acc[4][6];
  #pragma unroll
  for (int m = 0; m < 4; m++)
    #pragma unroll
    for (int t = 0; t < 6; t++) acc[m][t] = fzero;

  const unsigned short* wp[6];
  #pragma unroll
  for (int t = 0; t < 3; t++) {
    wp[2 * t]     = qkv_wb + (size_t)(t * 256 + wid * 32 + c) * 256 + g * 8;
    wp[2 * t + 1] = qkv_wb + (size_t)(t * 256 + wid * 32 + 16 + c) * 256 + g * 8;
  }
  #pragma unroll
  for (int kk = 0; kk < 8; kk++) {
    bf16x8 a[4];
    #pragma unroll
    for (int m = 0; m < 4; m++)
      a[m] = *(const bf16x8*)(xs + (m * 16 + c) * 264 + kk * 32 + g * 8);
    #pragma unroll
    for (int t = 0; t < 6; t++) {
      bf16x8 bf = *(const bf16x8*)(wp[t] + kk * 32);
      #pragma unroll
      for (int m = 0; m < 4; m++)
        acc[m][t] = __builtin_amdgcn_mfma_f32_16x16x32_bf16(a[m], bf, acc[m][t], 0, 0, 0);
    }
  }

  // ---- scatter q,k row-major [64][40]; v transposed [32][72] ----
  #pragma unroll
  for (int m = 0; m < 4; m++) {
    #pragma unroll
    for (int t = 0; t < 4; t++) {
      unsigned short* dst = (t < 2) ? qs : ks;
      int d = (t & 1) * 16 + c;
      #pragma unroll
      for (int jj = 0; jj < 4; jj++)
        dst[(m * 16 + g * 4 + jj) * 40 + d] = (unsigned short)f2bf1(acc[m][t][jj]);
    }
    #pragma unroll
    for (int t = 0; t < 2; t++) {
      int d = t * 16 + c;
      uint2 pk;
      pk.x = f2bf_pk(acc[m][4 + t][0], acc[m][4 + t][1]);
      pk.y = f2bf_pk(acc[m][4 + t][2], acc[m][4 + t][3]);
      *(uint2*)(vTs + d * 72 + m * 16 + g * 4) = pk;
    }
  }
  // per-wave private LDS + in-order DS within a wave: no barrier needed here.

  // ---- S^T = K·Q^T (q pre-scaled), + bias, softmax along kv ----
  bf16x8 kf[4], qf[4];
  #pragma unroll
  for (int ti = 0; ti < 4; ti++) kf[ti] = *(const bf16x8*)(ks + (ti * 16 + c) * 40 + g * 8);
  #pragma unroll
  for (int tj = 0; tj < 4; tj++) qf[tj] = *(const bf16x8*)(qs + (tj * 16 + c) * 40 + g * 8);

  f32x4 sl[4][4];
  #pragma unroll
  for (int ti = 0; ti < 4; ti++)
    #pragma unroll
    for (int tj = 0; tj < 4; tj++)
      sl[ti][tj] = __builtin_amdgcn_mfma_f32_16x16x32_bf16(kf[ti], qf[tj], fzero, 0, 0, 0);

  #pragma unroll
  for (int ti = 0; ti < 4; ti++)
    #pragma unroll
    for (int tj = 0; tj < 4; tj++) {
      f32x4 bv = *(const f32x4*)(bias_sw + ((size_t)((wid * 4 + ti) * 4 + tj) * 64 + lane) * 4);
      sl[ti][tj] += bv;
    }

  #pragma unroll
  for (int tj = 0; tj < 4; tj++) {
    float mx = -1e30f;
    #pragma unroll
    for (int ti = 0; ti < 4; ti++)
      #pragma unroll
      for (int jj = 0; jj < 4; jj++) mx = fmaxf(mx, sl[ti][tj][jj]);
    mx = fmaxf(mx, __shfl_xor(mx, 16, 64));
    mx = fmaxf(mx, __shfl_xor(mx, 32, 64));
    float p[4][4];
    float sum = 0.f;
    #pragma unroll
    for (int ti = 0; ti < 4; ti++)
      #pragma unroll
      for (int jj = 0; jj < 4; jj++) {
        float e = exp2f((sl[ti][tj][jj] - mx) * LOG2E);
        p[ti][jj] = e;
        sum += e;
      }
    sum += __shfl_xor(sum, 16, 64);
    sum += __shfl_xor(sum, 32, 64);
    float rinv = 1.0f / sum;
    #pragma unroll
    for (int ti = 0; ti < 4; ti++) {
      uint2 pk;
      pk.x = f2bf_pk(p[ti][0] * rinv, p[ti][1] * rinv);
      pk.y = f2bf_pk(p[ti][2] * rinv, p[ti][3] * rinv);
      *(uint2*)(Ps + (tj * 16 + c) * 72 + ti * 16 + g * 4) = pk;  // P row-major [q][kv]
    }
  }

  // ---- O = P·V ----
  f32x4 o[4][2];
  #pragma unroll
  for (int tq = 0; tq < 4; tq++) { o[tq][0] = fzero; o[tq][1] = fzero; }
  #pragma unroll
  for (int kv = 0; kv < 2; kv++) {
    bf16x8 pa[4], vb[2];
    #pragma unroll
    for (int tq = 0; tq < 4; tq++)
      pa[tq] = *(const bf16x8*)(Ps + (tq * 16 + c) * 72 + kv * 32 + g * 8);
    #pragma unroll
    for (int dt = 0; dt < 2; dt++)
      vb[dt] = *(const bf16x8*)(vTs + (dt * 16 + c) * 72 + kv * 32 + g * 8);
    #pragma unroll
    for (int tq = 0; tq < 4; tq++)
      #pragma unroll
      for (int dt = 0; dt < 2; dt++)
        o[tq][dt] = __builtin_amdgcn_mfma_f32_16x16x32_bf16(pa[tq], vb[dt], o[tq][dt], 0, 0, 0);
  }

  __syncthreads();   // everyone done reading xs (qkv phase)
  // ---- O -> xs [64][264] bf16, cols = head*32 + d ----
  #pragma unroll
  for (int tq = 0; tq < 4; tq++)
    #pragma unroll
    for (int dt = 0; dt < 2; dt++)
      #pragma unroll
      for (int jj = 0; jj < 4; jj++)
        xs[(tq * 16 + g * 4 + jj) * 264 + wid * 32 + dt * 16 + c] =
            (unsigned short)f2bf1(o[tq][dt][jj]);
  __syncthreads();

  // ---- out projection: wave handles cols [32*wid, 32*wid+32) ----
  f32x4 po[4][2];
  #pragma unroll
  for (int m = 0; m < 4; m++) { po[m][0] = fzero; po[m][1] = fzero; }
  const unsigned short* pw0 = proj_wb + (size_t)(wid * 32 + c) * 256 + g * 8;
  const unsigned short* pw1 = proj_wb + (size_t)(wid * 32 + 16 + c) * 256 + g * 8;
  #pragma unroll
  for (int kk = 0; kk < 8; kk++) {
    bf16x8 a[4];
    #pragma unroll
    for (int m = 0; m < 4; m++)
      a[m] = *(const bf16x8*)(xs + (m * 16 + c) * 264 + kk * 32 + g * 8);
    bf16x8 b0 = *(const bf16x8*)(pw0 + kk * 32);
    bf16x8 b1 = *(const bf16x8*)(pw1 + kk * 32);
    #pragma unroll
    for (int m = 0; m < 4; m++) {
      po[m][0] = __builtin_amdgcn_mfma_f32_16x16x32_bf16(a[m], b0, po[m][0], 0, 0, 0);
      po[m][1] = __builtin_amdgcn_mfma_f32_16x16x32_bf16(a[m], b1, po[m][1], 0, 0, 0);
    }
  }
  float pb0 = proj_b[wid * 32 + c], pb1 = proj_b[wid * 32 + 16 + c];
  float* ob = out + (size_t)b * 16384;
  #pragma unroll
  for (int m = 0; m < 4; m++)
    #pragma unroll
    for (int jj = 0; jj < 4; jj++) {
      int tok = m * 16 + g * 4 + jj;
      ob[tok * 256 + wid * 32 + c]      = po[m][0][jj] + pb0;
      ob[tok * 256 + wid * 32 + 16 + c] = po[m][1][jj] + pb1;
    }
}

extern "C" void kernel_launch(void* const* d_in, const int* in_sizes, int n_in,
                              void* d_out, int out_size, void* d_ws, size_t ws_size,
                              hipStream_t stream) {
  const float* x      = (const float*)d_in[0];
  const float* qkv_w  = (const float*)d_in[1];
  const float* proj_w = (const float*)d_in[2];
  const float* proj_b = (const float*)d_in[3];
  const float* cpb_w1 = (const float*)d_in[4];
  const float* cpb_b1 = (const float*)d_in[5];
  const float* cpb_w2 = (const float*)d_in[6];
  float* out = (float*)d_out;

  char* ws = (char*)d_ws;
  unsigned short* qkv_wb = (unsigned short*)(ws);            // 393216 B
  unsigned short* proj_wb = (unsigned short*)(ws + 393216);  // 131072 B
  float* t_buf   = (float*)(ws + 524288);                    // 7200 B
  float* bias_sw = (float*)(ws + 532480);                    // 131072 B

  prep_wts<<<dim3(256), dim3(256), 0, stream>>>(qkv_w, proj_w, qkv_wb, proj_wb);
  prep_cpb<<<dim3(225), dim3(64), 0, stream>>>(cpb_w1, cpb_b1, cpb_w2, t_buf);
  prep_bias<<<dim3(128), dim3(64), 0, stream>>>(t_buf, bias_sw);
  win_attn<<<dim3(4096), dim3(512), 152576, stream>>>(x, qkv_wb, proj_wb, proj_b, bias_sw, out);
}

// Round 2
// 369.969 us; speedup vs baseline: 1.3288x; 1.3288x over previous
//
#include <hip/hip_runtime.h>
#include <stdint.h>

#define LOG2E 1.44269504088896340f

typedef __attribute__((ext_vector_type(4))) float f32x4;
typedef __attribute__((ext_vector_type(8))) short bf16x8;

__device__ __forceinline__ unsigned int f2bf1(float f) {
  unsigned int u = __builtin_bit_cast(unsigned int, f);
  u += 0x7fffu + ((u >> 16) & 1u);   // RNE to bf16
  return u >> 16;
}
__device__ __forceinline__ unsigned int f2bf_pk(float lo, float hi) {
  return f2bf1(lo) | (f2bf1(hi) << 16);
}
__device__ __forceinline__ bf16x8 pack8(f32x4 a, f32x4 b) {
  union { uint4 u; bf16x8 v; } r;
  r.u.x = f2bf_pk(a[0], a[1]);
  r.u.y = f2bf_pk(a[2], a[3]);
  r.u.z = f2bf_pk(b[0], b[1]);
  r.u.w = f2bf_pk(b[2], b[3]);
  return r.v;
}

// ---------------- prep kernels (run every call; deterministic) ----------------

__global__ void prep_wts(const float* __restrict__ qkv_w, const float* __restrict__ proj_w,
                         unsigned short* __restrict__ qkv_wb, unsigned short* __restrict__ proj_wb) {
  int i = blockIdx.x * blockDim.x + threadIdx.x;
  int stride = gridDim.x * blockDim.x;
  for (int idx = i; idx < 768 * 256; idx += stride) {
    float v = qkv_w[idx];
    if (idx < 256 * 256) v *= 0.17677669529663687f;  // fold 1/sqrt(32) into q
    qkv_wb[idx] = (unsigned short)f2bf1(v);
  }
  for (int idx = i; idx < 256 * 256; idx += stride)
    proj_wb[idx] = (unsigned short)f2bf1(proj_w[idx]);
}

__global__ void prep_cpb(const float* __restrict__ w1, const float* __restrict__ b1,
                         const float* __restrict__ w2, float* __restrict__ t_buf) {
  int row = blockIdx.x;        // 0..224
  int l = threadIdx.x;         // 0..63
  int a = row / 15, bb = row % 15;
  float va = (a - 7) * (8.0f / 7.0f);
  float vb = (bb - 7) * (8.0f / 7.0f);
  float x0 = (va > 0.f ? 1.f : (va < 0.f ? -1.f : 0.f)) * log2f(fabsf(va) + 1.0f) * (1.0f / 3.0f);
  float x1 = (vb > 0.f ? 1.f : (vb < 0.f ? -1.f : 0.f)) * log2f(fabsf(vb) + 1.0f) * (1.0f / 3.0f);
  float acc[8];
  #pragma unroll
  for (int o = 0; o < 8; o++) acc[o] = 0.f;
  for (int jj = 0; jj < 8; jj++) {
    int j = jj * 64 + l;
    float h = fmaf(x0, w1[2 * j], fmaf(x1, w1[2 * j + 1], b1[j]));
    h = fmaxf(h, 0.f);
    #pragma unroll
    for (int o = 0; o < 8; o++) acc[o] = fmaf(h, w2[o * 512 + j], acc[o]);
  }
  #pragma unroll
  for (int m = 1; m < 64; m <<= 1) {
    #pragma unroll
    for (int o = 0; o < 8; o++) acc[o] += __shfl_xor(acc[o], m, 64);
  }
  if (l < 8) t_buf[row * 8 + l] = acc[l];
}

// bias_sw[h][ti][tj][lane][jj]: q = tj*16+(lane&15), kv = ti*16+(lane>>4)*4+jj
__global__ void prep_bias(const float* __restrict__ t_buf, float* __restrict__ bias_sw) {
  int blk = blockIdx.x;   // h*16 + ti*4 + tj
  int l = threadIdx.x;
  int h = blk >> 4, ti = (blk >> 2) & 3, tj = blk & 3;
  int q = tj * 16 + (l & 15);
  int kvb = ti * 16 + (l >> 4) * 4;
  int qi = q >> 3, qj = q & 7;
  #pragma unroll
  for (int jj = 0; jj < 4; jj++) {
    int kv = kvb + jj, ki = kv >> 3, kj = kv & 7;
    int idx = (qi - ki + 7) * 15 + (qj - kj + 7);
    float tv = t_buf[idx * 8 + h];
    float s = 16.0f / (1.0f + exp2f(-tv * LOG2E));
    bias_sw[(blk * 64 + l) * 4 + jj] = s;
  }
}

// ---------------- fused main kernel ----------------
// grid 4096, 512 threads = 8 waves, wave = head. LDS: xs[64][264] + per-wave
// vT[32][68] = 68608 B -> 2 blocks/CU. Q,K,P never touch LDS (in-register
// fragment packing via the free k-axis permutation pi(g,j)).
__global__ __launch_bounds__(512, 4)
void win_attn(const float* __restrict__ x, const unsigned short* __restrict__ qkv_wb,
              const unsigned short* __restrict__ proj_wb, const float* __restrict__ proj_b,
              const float* __restrict__ bias_sw, float* __restrict__ out) {
  extern __shared__ char smem[];
  const int b = blockIdx.x;
  const int tid = threadIdx.x;
  const int wid = tid >> 6;        // head
  const int lane = tid & 63;
  const int c = lane & 15, g = lane >> 4;
  const f32x4 fzero = {0.f, 0.f, 0.f, 0.f};

  unsigned short* xs  = (unsigned short*)smem;                         // [64][264]
  unsigned short* vTs = (unsigned short*)(smem + 33792 + wid * 4352);  // [32][68]

  // ---- stage x -> LDS bf16 ----
  {
    const float* xb = x + (size_t)b * 16384;
    int row = tid >> 3, cb = (tid & 7) * 32;
    const float4* src = (const float4*)(xb + row * 256 + cb);
    #pragma unroll
    for (int qq = 0; qq < 4; qq++) {
      float4 f0 = src[2 * qq], f1 = src[2 * qq + 1];
      uint4 pk;
      pk.x = f2bf_pk(f0.x, f0.y);
      pk.y = f2bf_pk(f0.z, f0.w);
      pk.z = f2bf_pk(f1.x, f1.y);
      pk.w = f2bf_pk(f1.z, f1.w);
      *(uint4*)(xs + row * 264 + cb + qq * 8) = pk;
    }
  }
  __syncthreads();

  // ---- pass A: V = x @ Wv^T (token-major), scatter to vT[d][token] ----
  f32x4 av[4][2];
  #pragma unroll
  for (int t = 0; t < 4; t++) { av[t][0] = fzero; av[t][1] = fzero; }
  {
    const unsigned short* wv0 = qkv_wb + (size_t)(512 + wid * 32 + c) * 256 + g * 8;
    const unsigned short* wv1 = qkv_wb + (size_t)(512 + wid * 32 + 16 + c) * 256 + g * 8;
    #pragma unroll
    for (int kk = 0; kk < 8; kk++) {
      bf16x8 xf[4];
      #pragma unroll
      for (int t = 0; t < 4; t++)
        xf[t] = *(const bf16x8*)(xs + (t * 16 + c) * 264 + kk * 32 + g * 8);
      bf16x8 w0 = *(const bf16x8*)(wv0 + kk * 32);
      bf16x8 w1 = *(const bf16x8*)(wv1 + kk * 32);
      #pragma unroll
      for (int t = 0; t < 4; t++) {
        av[t][0] = __builtin_amdgcn_mfma_f32_16x16x32_bf16(xf[t], w0, av[t][0], 0, 0, 0);
        av[t][1] = __builtin_amdgcn_mfma_f32_16x16x32_bf16(xf[t], w1, av[t][1], 0, 0, 0);
      }
    }
  }
  #pragma unroll
  for (int t = 0; t < 4; t++)
    #pragma unroll
    for (int fv = 0; fv < 2; fv++) {
      uint2 pk;
      pk.x = f2bf_pk(av[t][fv][0], av[t][fv][1]);
      pk.y = f2bf_pk(av[t][fv][2], av[t][fv][3]);
      *(uint2*)(vTs + (fv * 16 + c) * 68 + t * 16 + g * 4) = pk;   // row d, col token
    }

  // ---- pass B: Q,K d-major: C[feature][token] = mfma(Wq/k, x^T) ----
  f32x4 aq[2][4], ak[2][4];
  #pragma unroll
  for (int f = 0; f < 2; f++)
    #pragma unroll
    for (int t = 0; t < 4; t++) { aq[f][t] = fzero; ak[f][t] = fzero; }
  {
    const unsigned short* wq[2], *wk[2];
    #pragma unroll
    for (int f = 0; f < 2; f++) {
      wq[f] = qkv_wb + (size_t)(wid * 32 + f * 16 + c) * 256 + g * 8;
      wk[f] = qkv_wb + (size_t)(256 + wid * 32 + f * 16 + c) * 256 + g * 8;
    }
    #pragma unroll
    for (int kk = 0; kk < 8; kk++) {
      bf16x8 xf[4];
      #pragma unroll
      for (int t = 0; t < 4; t++)
        xf[t] = *(const bf16x8*)(xs + (t * 16 + c) * 264 + kk * 32 + g * 8);
      #pragma unroll
      for (int f = 0; f < 2; f++) {
        bf16x8 wfq = *(const bf16x8*)(wq[f] + kk * 32);
        bf16x8 wfk = *(const bf16x8*)(wk[f] + kk * 32);
        #pragma unroll
        for (int t = 0; t < 4; t++) {
          aq[f][t] = __builtin_amdgcn_mfma_f32_16x16x32_bf16(wfq, xf[t], aq[f][t], 0, 0, 0);
          ak[f][t] = __builtin_amdgcn_mfma_f32_16x16x32_bf16(wfk, xf[t], ak[f][t], 0, 0, 0);
        }
      }
    }
  }

  // pack fragments in-register: lane (c,g) holds d = {4g..4g+3} u {16+4g..16+4g+3}
  bf16x8 kf[4], qf[4];
  #pragma unroll
  for (int t = 0; t < 4; t++) {
    kf[t] = pack8(ak[0][t], ak[1][t]);
    qf[t] = pack8(aq[0][t], aq[1][t]);
  }

  // ---- S^T = K Q^T + bias ----
  f32x4 sl[4][4];
  #pragma unroll
  for (int ti = 0; ti < 4; ti++)
    #pragma unroll
    for (int tj = 0; tj < 4; tj++)
      sl[ti][tj] = __builtin_amdgcn_mfma_f32_16x16x32_bf16(kf[ti], qf[tj], fzero, 0, 0, 0);

  #pragma unroll
  for (int ti = 0; ti < 4; ti++)
    #pragma unroll
    for (int tj = 0; tj < 4; tj++)
      sl[ti][tj] += *(const f32x4*)(bias_sw + ((size_t)((wid * 4 + ti) * 4 + tj) * 64 + lane) * 4);

  // ---- softmax along kv (in-lane ti,jj + shfl over g), pack P fragments ----
  bf16x8 pb[4][2];
  #pragma unroll
  for (int tj = 0; tj < 4; tj++) {
    float mx = -1e30f;
    #pragma unroll
    for (int ti = 0; ti < 4; ti++)
      #pragma unroll
      for (int jj = 0; jj < 4; jj++) mx = fmaxf(mx, sl[ti][tj][jj]);
    mx = fmaxf(mx, __shfl_xor(mx, 16, 64));
    mx = fmaxf(mx, __shfl_xor(mx, 32, 64));
    f32x4 pr[4];
    float sum = 0.f;
    #pragma unroll
    for (int ti = 0; ti < 4; ti++)
      #pragma unroll
      for (int jj = 0; jj < 4; jj++) {
        float e = exp2f((sl[ti][tj][jj] - mx) * LOG2E);
        pr[ti][jj] = e;
        sum += e;
      }
    sum += __shfl_xor(sum, 16, 64);
    sum += __shfl_xor(sum, 32, 64);
    float rinv = 1.0f / sum;
    pb[tj][0] = pack8(pr[0] * rinv, pr[1] * rinv);
    pb[tj][1] = pack8(pr[2] * rinv, pr[3] * rinv);
  }

  // ---- O^T = V^T P^T : A-frag from vT (cols 4g / 16+4g), B-frag = pb ----
  f32x4 o[2][4];
  #pragma unroll
  for (int dt = 0; dt < 2; dt++)
    #pragma unroll
    for (int tq = 0; tq < 4; tq++) o[dt][tq] = fzero;
  #pragma unroll
  for (int h = 0; h < 2; h++) {
    bf16x8 vf[2];
    #pragma unroll
    for (int dt = 0; dt < 2; dt++) {
      union { uint4 u; bf16x8 v; } vv;
      uint2 lo = *(const uint2*)(vTs + (dt * 16 + c) * 68 + h * 32 + g * 4);
      uint2 hi = *(const uint2*)(vTs + (dt * 16 + c) * 68 + h * 32 + 16 + g * 4);
      vv.u.x = lo.x; vv.u.y = lo.y; vv.u.z = hi.x; vv.u.w = hi.y;
      vf[dt] = vv.v;
    }
    #pragma unroll
    for (int dt = 0; dt < 2; dt++)
      #pragma unroll
      for (int tq = 0; tq < 4; tq++)
        o[dt][tq] = __builtin_amdgcn_mfma_f32_16x16x32_bf16(vf[dt], pb[tq][h], o[dt][tq], 0, 0, 0);
  }

  __syncthreads();   // all waves done reading xs
  // ---- O -> xs: lane holds O[token=tq*16+c][d = dt*16+4g+jj] ----
  #pragma unroll
  for (int tq = 0; tq < 4; tq++)
    #pragma unroll
    for (int dt = 0; dt < 2; dt++) {
      uint2 pk;
      pk.x = f2bf_pk(o[dt][tq][0], o[dt][tq][1]);
      pk.y = f2bf_pk(o[dt][tq][2], o[dt][tq][3]);
      *(uint2*)(xs + (tq * 16 + c) * 264 + wid * 32 + dt * 16 + g * 4) = pk;
    }
  __syncthreads();

  // ---- out projection (token-major) ----
  f32x4 po[4][2];
  #pragma unroll
  for (int m = 0; m < 4; m++) { po[m][0] = fzero; po[m][1] = fzero; }
  const unsigned short* pw0 = proj_wb + (size_t)(wid * 32 + c) * 256 + g * 8;
  const unsigned short* pw1 = proj_wb + (size_t)(wid * 32 + 16 + c) * 256 + g * 8;
  #pragma unroll
  for (int kk = 0; kk < 8; kk++) {
    bf16x8 a[4];
    #pragma unroll
    for (int m = 0; m < 4; m++)
      a[m] = *(const bf16x8*)(xs + (m * 16 + c) * 264 + kk * 32 + g * 8);
    bf16x8 b0 = *(const bf16x8*)(pw0 + kk * 32);
    bf16x8 b1 = *(const bf16x8*)(pw1 + kk * 32);
    #pragma unroll
    for (int m = 0; m < 4; m++) {
      po[m][0] = __builtin_amdgcn_mfma_f32_16x16x32_bf16(a[m], b0, po[m][0], 0, 0, 0);
      po[m][1] = __builtin_amdgcn_mfma_f32_16x16x32_bf16(a[m], b1, po[m][1], 0, 0, 0);
    }
  }
  float pb0 = proj_b[wid * 32 + c], pb1 = proj_b[wid * 32 + 16 + c];
  float* ob = out + (size_t)b * 16384;
  #pragma unroll
  for (int m = 0; m < 4; m++)
    #pragma unroll
    for (int jj = 0; jj < 4; jj++) {
      int tok = m * 16 + g * 4 + jj;
      ob[tok * 256 + wid * 32 + c]      = po[m][0][jj] + pb0;
      ob[tok * 256 + wid * 32 + 16 + c] = po[m][1][jj] + pb1;
    }
}

extern "C" void kernel_launch(void* const* d_in, const int* in_sizes, int n_in,
                              void* d_out, int out_size, void* d_ws, size_t ws_size,
                              hipStream_t stream) {
  const float* x      = (const float*)d_in[0];
  const float* qkv_w  = (const float*)d_in[1];
  const float* proj_w = (const float*)d_in[2];
  const float* proj_b = (const float*)d_in[3];
  const float* cpb_w1 = (const float*)d_in[4];
  const float* cpb_b1 = (const float*)d_in[5];
  const float* cpb_w2 = (const float*)d_in[6];
  float* out = (float*)d_out;

  char* ws = (char*)d_ws;
  unsigned short* qkv_wb = (unsigned short*)(ws);            // 393216 B
  unsigned short* proj_wb = (unsigned short*)(ws + 393216);  // 131072 B
  float* t_buf   = (float*)(ws + 524288);                    // 7200 B
  float* bias_sw = (float*)(ws + 532480);                    // 131072 B

  prep_wts<<<dim3(256), dim3(256), 0, stream>>>(qkv_w, proj_w, qkv_wb, proj_wb);
  prep_cpb<<<dim3(225), dim3(64), 0, stream>>>(cpb_w1, cpb_b1, cpb_w2, t_buf);
  prep_bias<<<dim3(128), dim3(64), 0, stream>>>(t_buf, bias_sw);
  win_attn<<<dim3(4096), dim3(512), 68608, stream>>>(x, qkv_wb, proj_wb, proj_b, bias_sw, out);
}